// Round 5
// baseline (288.826 us; speedup 1.0000x reference)
//
#include <hip/hip_runtime.h>
#include <hip/hip_bf16.h>

#define H 128
#define W 128
#define C 64
#define NB 8

typedef __attribute__((ext_vector_type(4))) float f32x4;
typedef __attribute__((ext_vector_type(8))) short short8;

// ws layout (bytes)
static constexpr size_t XT_B  = 0;         // bf16 xt [N][H][W][C]   16777216 B
static constexpr size_t CD_B  = 16777216;  // float2 cd [N][9][H][W]  9437184 B
static constexpr size_t WT_B  = 26214400;  // bf16 wt [9][co][c]        73728 B
static constexpr size_t WO_B  = 26288128;  // bf16 wo [9][32(o)][c]     36864 B
static constexpr size_t SUM_B = 26324992;  // f32 sums [4][128]          2048 B

__device__ __forceinline__ ushort f2bf(float f) {
  uint u = __float_as_uint(f);
  return (ushort)((u + 0x7fffu + ((u >> 16) & 1u)) >> 16);
}

union PackBF { __hip_bfloat162 h[4]; short8 s; };

#define UNPACK_FMA(q, wgt, m)                                  \
  m[0] += (wgt) * __uint_as_float((q).x << 16);                \
  m[1] += (wgt) * __uint_as_float((q).x & 0xffff0000u);        \
  m[2] += (wgt) * __uint_as_float((q).y << 16);                \
  m[3] += (wgt) * __uint_as_float((q).y & 0xffff0000u);        \
  m[4] += (wgt) * __uint_as_float((q).z << 16);                \
  m[5] += (wgt) * __uint_as_float((q).z & 0xffff0000u);        \
  m[6] += (wgt) * __uint_as_float((q).w << 16);                \
  m[7] += (wgt) * __uint_as_float((q).w & 0xffff0000u);

// ---------------- prep: x NCHW->NHWC bf16; w -> wt[k][co][c]; w_off -> wo[k][o][c]; zero sums
__global__ __launch_bounds__(256) void prep_kernel(const float* __restrict__ x,
                                                   const float* __restrict__ w,
                                                   const float* __restrict__ w_off,
                                                   ushort* __restrict__ xt,
                                                   ushort* __restrict__ wt,
                                                   ushort* __restrict__ wo,
                                                   float* __restrict__ sums) {
  int b = blockIdx.x, t = threadIdx.x;
  if (b < 1024) {
    __shared__ float lds[64 * 129];
    int n = b >> 7, h = b & 127;
    const float* xp = x + ((size_t)n * C) * H * W + (size_t)h * W;
    for (int i = t; i < 8192; i += 256) {
      int c = i >> 7, ww = i & 127;
      lds[c * 129 + ww] = xp[(size_t)c * H * W + ww];
    }
    __syncthreads();
    ushort* xo = xt + (((size_t)n * H + h) * W) * C;
    for (int i = t; i < 8192; i += 256) {
      int ww = i >> 6, c = i & 63;
      xo[(size_t)ww * C + c] = f2bf(lds[c * 129 + ww]);
    }
  } else if (b < 1040) {
    int base = (b - 1024) * 2304;
    for (int i = t; i < 2304; i += 256) {
      int idx = base + i;               // idx = co*576 + c*9 + kk
      int co = idx / 576;
      int rem = idx % 576;
      int c = rem / 9, kk = rem % 9;
      wt[(size_t)kk * 4096 + co * 64 + c] = f2bf(w[idx]);
    }
  } else if (b < 1048) {
    int base = (b - 1040) * 2304;
    for (int i = t; i < 2304; i += 256) {
      int idx = base + i;               // idx = k*2048 + o*64 + c
      int k = idx >> 11, o = (idx >> 6) & 31, c = idx & 63;
      wo[idx] = (o < 18) ? f2bf(w_off[((size_t)(o * 64 + c)) * 9 + k]) : (ushort)0;
    }
  } else {
    // zero ALL 512 sum slots (4 atomic-reduction copies x 128)
    sums[t] = 0.0f;
    sums[t + 256] = 0.0f;
  }
}

// ---------------- offset conv via bf16 MFMA; all 18 gather loads prefetched up-front
__global__ __launch_bounds__(256, 4) void offs_kernel(const ushort* __restrict__ xt,
                                                      const ushort* __restrict__ wo,
                                                      const float* __restrict__ b_off,
                                                      float2* __restrict__ cd) {
  int b = blockIdx.x;
  int n = b >> 8;
  int tile = b & 255;
  int ty0 = (tile >> 4) << 3;
  int tx0 = (tile & 15) << 3;
  int t = threadIdx.x;
  int wv = t >> 6, ln = t & 63;
  int lr = ln & 15, lg = ln >> 4;
  int mypos = wv * 16 + lr;
  int ph = ty0 + (mypos >> 3), pw = tx0 + (mypos & 7);
  int cb = lg << 3;
  const ushort* xtn = xt + ((size_t)n << 20);

  // prefetch ALL 9 taps' x rows (static addresses) — one memory latency total
  uint4 qa[9], qb[9];
#pragma unroll
  for (int k = 0; k < 9; ++k) {
    int gy = ph + k / 3 - 1, gx = pw + k % 3 - 1;
    int gyc = min(max(gy, 0), H - 1), gxc = min(max(gx, 0), W - 1);
    uint p = (uint)((gyc << 7) + gxc) << 6;
    qa[k] = *(const uint4*)(xtn + p + cb);
    qb[k] = *(const uint4*)(xtn + p + cb + 32);
  }

  f32x4 acc0 = {0.f, 0.f, 0.f, 0.f}, acc1 = {0.f, 0.f, 0.f, 0.f};
#pragma unroll
  for (int k = 0; k < 9; ++k) {
    int gy = ph + k / 3 - 1, gx = pw + k % 3 - 1;
    bool v = (gy >= 0) & (gy < H) & (gx >= 0) & (gx < W);
    uint msk = v ? 0xffffffffu : 0u;
    short8 sa, sb;
    {
      uint4 a = qa[k], bq = qb[k];
      a.x &= msk; a.y &= msk; a.z &= msk; a.w &= msk;
      bq.x &= msk; bq.y &= msk; bq.z &= msk; bq.w &= msk;
      sa = *(short8*)&a; sb = *(short8*)&bq;
    }
    const ushort* wk = wo + (k << 11);
    short8 b00 = *(const short8*)(wk + (lr << 6) + cb);
    short8 b01 = *(const short8*)(wk + (lr << 6) + 32 + cb);
    short8 b10 = *(const short8*)(wk + ((16 + lr) << 6) + cb);
    short8 b11 = *(const short8*)(wk + ((16 + lr) << 6) + 32 + cb);
    acc0 = __builtin_amdgcn_mfma_f32_16x16x32_bf16(sa, b00, acc0, 0, 0, 0);
    acc0 = __builtin_amdgcn_mfma_f32_16x16x32_bf16(sb, b01, acc0, 0, 0, 0);
    acc1 = __builtin_amdgcn_mfma_f32_16x16x32_bf16(sa, b10, acc1, 0, 0, 0);
    acc1 = __builtin_amdgcn_mfma_f32_16x16x32_bf16(sb, b11, acc1, 0, 0, 0);
  }
  // D[pos][o]: lane holds o = ot*16+lr (cols), pos = wv*16 + lg*4 + r (rows)
  float bo0 = b_off[lr];
  float bo1 = (lr < 2) ? b_off[16 + lr] : 0.f;
  int rh[4], rw[4];
#pragma unroll
  for (int r = 0; r < 4; ++r) {
    int pos = wv * 16 + lg * 4 + r;
    rh[r] = ty0 + (pos >> 3);
    rw[r] = tx0 + (pos & 7);
  }
  float v0[4], p0[4], v1[4], p1[4];
#pragma unroll
  for (int r = 0; r < 4; ++r) { v0[r] = acc0[r] + bo0; v1[r] = acc1[r] + bo1; }
#pragma unroll
  for (int r = 0; r < 4; ++r) { p0[r] = __shfl_xor(v0[r], 1); p1[r] = __shfl_xor(v1[r], 1); }
  if (!(lr & 1)) {
    int k = lr >> 1;  // 0..7
    int ky = k / 3 - 1, kx = k % 3 - 1;
    float2* cdn = cd + (((size_t)n * 9 + k) << 14);
#pragma unroll
    for (int r = 0; r < 4; ++r)
      cdn[(rh[r] << 7) + rw[r]] = make_float2((float)(rh[r] + ky) + v0[r],
                                              (float)(rw[r] + kx) + p0[r]);
    if (lr == 0) {
      float2* cd8 = cd + (((size_t)n * 9 + 8) << 14);
#pragma unroll
      for (int r = 0; r < 4; ++r)
        cd8[(rh[r] << 7) + rw[r]] = make_float2((float)(rh[r] + 1) + v1[r],
                                                (float)(rw[r] + 1) + p1[r]);
    }
  }
}

// ---------------- deformable conv: depth-2 software-pipelined gather -> bf16 MFMA
__global__ __launch_bounds__(256, 4) void conv_kernel(const ushort* __restrict__ xt,
                                                      const float2* __restrict__ cd,
                                                      const ushort* __restrict__ wt,
                                                      const float* __restrict__ bias,
                                                      float* __restrict__ out,
                                                      float* __restrict__ sums) {
  int b = blockIdx.x;
  int n = b >> 8;
  int tile = b & 255;
  int ty0 = (tile >> 4) << 3;
  int tx0 = (tile & 15) << 3;
  int t = threadIdx.x;
  int wv = t >> 6, ln = t & 63;
  int lr = ln & 15, lg = ln >> 4;
  int mypos = wv * 16 + lr;
  int ph = ty0 + (mypos >> 3), pw = tx0 + (mypos & 7);
  int cb = lg << 3;

  __shared__ float red[4][64][2];

  const ushort* xtn = xt + ((size_t)n << 20);
  const float2* cdn = cd + (((size_t)n * 9) << 14) + (ph << 7) + pw;

  f32x4 acc[4];
#pragma unroll
  for (int ct = 0; ct < 4; ++ct) acc[ct] = (f32x4)(0.f);

  float2 cd2[2];      // coord ring (depth 2)
  uint4 g[2][8];      // gather ring (depth 2)
  float wg[2][4];     // bilinear weight ring

  // issue tap kk's 8 gather loads + weights into slot kk&1 (coords must be resident)
#define ISSUE(kk) {                                                        \
    const int s_ = (kk) & 1;                                               \
    float ys = cd2[s_].x, xs = cd2[s_].y;                                  \
    float y0f = floorf(ys), x0f = floorf(xs);                              \
    float wy = ys - y0f, wx = xs - x0f;                                    \
    int iy0 = (int)y0f, ix0 = (int)x0f;                                    \
    int iy1 = iy0 + 1, ix1 = ix0 + 1;                                      \
    bool y0v = (iy0 >= 0) & (iy0 < H);                                     \
    bool y1v = (iy1 >= 0) & (iy1 < H);                                     \
    bool x0v = (ix0 >= 0) & (ix0 < W);                                     \
    bool x1v = (ix1 >= 0) & (ix1 < W);                                     \
    int yc0 = min(max(iy0, 0), H - 1), yc1 = min(max(iy1, 0), H - 1);      \
    int xc0 = min(max(ix0, 0), W - 1), xc1 = min(max(ix1, 0), W - 1);      \
    wg[s_][0] = (1.f - wy) * (1.f - wx) * (float)(y0v & x0v);              \
    wg[s_][1] = (1.f - wy) * wx * (float)(y0v & x1v);                      \
    wg[s_][2] = wy * (1.f - wx) * (float)(y1v & x0v);                      \
    wg[s_][3] = wy * wx * (float)(y1v & x1v);                              \
    uint p00 = (uint)((yc0 << 7) + xc0) << 6;                              \
    uint p01 = (uint)((yc0 << 7) + xc1) << 6;                              \
    uint p10 = (uint)((yc1 << 7) + xc0) << 6;                              \
    uint p11 = (uint)((yc1 << 7) + xc1) << 6;                              \
    g[s_][0] = *(const uint4*)(xtn + p00 + cb);                            \
    g[s_][1] = *(const uint4*)(xtn + p00 + cb + 32);                       \
    g[s_][2] = *(const uint4*)(xtn + p01 + cb);                            \
    g[s_][3] = *(const uint4*)(xtn + p01 + cb + 32);                       \
    g[s_][4] = *(const uint4*)(xtn + p10 + cb);                            \
    g[s_][5] = *(const uint4*)(xtn + p10 + cb + 32);                       \
    g[s_][6] = *(const uint4*)(xtn + p11 + cb);                            \
    g[s_][7] = *(const uint4*)(xtn + p11 + cb + 32);                       \
  }

  cd2[0] = cdn[0];
  cd2[1] = cdn[(size_t)1 << 14];
  ISSUE(0);

#pragma unroll
  for (int k = 0; k < 9; ++k) {
    if (k < 8) ISSUE(k + 1);                                   // next tap's loads in flight
    if (k < 7) cd2[k & 1] = cdn[(size_t)(k + 2) << 14];        // coord ring depth 2
    {
      const int s_ = k & 1;
      float m0[8] = {0.f, 0.f, 0.f, 0.f, 0.f, 0.f, 0.f, 0.f};
      float m1[8] = {0.f, 0.f, 0.f, 0.f, 0.f, 0.f, 0.f, 0.f};
      UNPACK_FMA(g[s_][0], wg[s_][0], m0); UNPACK_FMA(g[s_][1], wg[s_][0], m1);
      UNPACK_FMA(g[s_][2], wg[s_][1], m0); UNPACK_FMA(g[s_][3], wg[s_][1], m1);
      UNPACK_FMA(g[s_][4], wg[s_][2], m0); UNPACK_FMA(g[s_][5], wg[s_][2], m1);
      UNPACK_FMA(g[s_][6], wg[s_][3], m0); UNPACK_FMA(g[s_][7], wg[s_][3], m1);
      PackBF a0, a1;
#pragma unroll
      for (int j = 0; j < 4; ++j) {
        a0.h[j] = __float22bfloat162_rn(make_float2(m0[2 * j], m0[2 * j + 1]));
        a1.h[j] = __float22bfloat162_rn(make_float2(m1[2 * j], m1[2 * j + 1]));
      }
      const ushort* wk = wt + (k << 12) + (lr << 6) + cb;
#pragma unroll
      for (int ct = 0; ct < 4; ++ct) {
        short8 b0 = *(const short8*)(wk + (ct << 10));
        short8 b1 = *(const short8*)(wk + (ct << 10) + 32);
        acc[ct] = __builtin_amdgcn_mfma_f32_16x16x32_bf16(a0.s, b0, acc[ct], 0, 0, 0);
        acc[ct] = __builtin_amdgcn_mfma_f32_16x16x32_bf16(a1.s, b1, acc[ct], 0, 0, 0);
      }
    }
  }
#undef ISSUE

  // epilogue: D[pos][co]; lane: co = ct*16+lr, pos = wv*16 + lg*4 + r
  float bi[4];
#pragma unroll
  for (int ct = 0; ct < 4; ++ct) bi[ct] = bias[ct * 16 + lr];
  int phw[4];
#pragma unroll
  for (int r = 0; r < 4; ++r) {
    int pos = wv * 16 + lg * 4 + r;
    phw[r] = ((ty0 + (pos >> 3)) << 7) + tx0 + (pos & 7);
  }
  float s1[4], s2[4];
#pragma unroll
  for (int ct = 0; ct < 4; ++ct) { s1[ct] = 0.f; s2[ct] = 0.f; }
#pragma unroll
  for (int ct = 0; ct < 4; ++ct) {
    size_t cbase = ((size_t)(n * 64 + ct * 16 + lr)) << 14;
#pragma unroll
    for (int r = 0; r < 4; ++r) {
      float v = acc[ct][r] + bi[ct];
      out[cbase + phw[r]] = v;
      s1[ct] += v;
      s2[ct] += v * v;
    }
  }
#pragma unroll
  for (int ct = 0; ct < 4; ++ct) {
    s1[ct] += __shfl_xor(s1[ct], 16);
    s1[ct] += __shfl_xor(s1[ct], 32);
    s2[ct] += __shfl_xor(s2[ct], 16);
    s2[ct] += __shfl_xor(s2[ct], 32);
  }
  if (lg == 0) {
#pragma unroll
    for (int ct = 0; ct < 4; ++ct) {
      red[wv][ct * 16 + lr][0] = s1[ct];
      red[wv][ct * 16 + lr][1] = s2[ct];
    }
  }
  __syncthreads();
  if (t < 128) {
    int co = t & 63, j = t >> 6;
    float s = red[0][co][j] + red[1][co][j] + red[2][co][j] + red[3][co][j];
    atomicAdd(&sums[(b & 3) * 128 + j * 64 + co], s);
  }
}

// ---------------- BN apply (in place on d_out)
__global__ __launch_bounds__(256) void bn_kernel(float* __restrict__ out,
                                                 const float* __restrict__ sums,
                                                 const float* __restrict__ gamma,
                                                 const float* __restrict__ beta) {
  size_t i4 = (size_t)blockIdx.x * 256 + threadIdx.x;
  size_t e = i4 * 4;
  int co = (int)((e >> 14) & 63);
  float s1 = sums[co] + sums[128 + co] + sums[256 + co] + sums[384 + co];
  float s2 = sums[64 + co] + sums[192 + co] + sums[320 + co] + sums[448 + co];
  const float inv_n = 1.f / 131072.f;
  float mean = s1 * inv_n;
  float var = s2 * inv_n - mean * mean;
  float iv = rsqrtf(var + 1e-5f);
  float sc = gamma[co] * iv;
  float sh = beta[co] - mean * sc;
  float4 v = ((float4*)out)[i4];
  v.x = v.x * sc + sh;
  v.y = v.y * sc + sh;
  v.z = v.z * sc + sh;
  v.w = v.w * sc + sh;
  ((float4*)out)[i4] = v;
}

extern "C" void kernel_launch(void* const* d_in, const int* in_sizes, int n_in,
                              void* d_out, int out_size, void* d_ws, size_t ws_size,
                              hipStream_t stream) {
  (void)in_sizes; (void)n_in; (void)out_size; (void)ws_size;
  const float* x     = (const float*)d_in[0];
  const float* w_off = (const float*)d_in[1];
  const float* b_off = (const float*)d_in[2];
  const float* w     = (const float*)d_in[3];
  const float* bias  = (const float*)d_in[4];
  const float* gamma = (const float*)d_in[5];
  const float* beta  = (const float*)d_in[6];
  uint8_t* wsb = (uint8_t*)d_ws;
  ushort* xtp  = (ushort*)(wsb + XT_B);
  float2* cdp  = (float2*)(wsb + CD_B);
  ushort* wtp  = (ushort*)(wsb + WT_B);
  ushort* wop  = (ushort*)(wsb + WO_B);
  float* sums  = (float*)(wsb + SUM_B);
  float* out   = (float*)d_out;

  hipLaunchKernelGGL(prep_kernel, dim3(1049), dim3(256), 0, stream, x, w, w_off, xtp, wtp, wop, sums);
  hipLaunchKernelGGL(offs_kernel, dim3(2048), dim3(256), 0, stream, xtp, wop, b_off, cdp);
  hipLaunchKernelGGL(conv_kernel, dim3(2048), dim3(256), 0, stream, xtp, cdp, wtp, bias, out, sums);
  hipLaunchKernelGGL(bn_kernel, dim3(8192), dim3(256), 0, stream, out, sums, gamma, beta);
}

// Round 6
// 168.520 us; speedup vs baseline: 1.7139x; 1.7139x over previous
//
#include <hip/hip_runtime.h>
#include <hip/hip_bf16.h>

#define H 128
#define W 128
#define C 64
#define NB 8

typedef __attribute__((ext_vector_type(4))) float f32x4;
typedef __attribute__((ext_vector_type(8))) short short8;

// ws layout (bytes)
static constexpr size_t XT_B  = 0;         // bf16 xt [N][H][W][C]   16777216 B
static constexpr size_t CD_B  = 16777216;  // float2 cd [N][9][H][W]  9437184 B
static constexpr size_t WT_B  = 26214400;  // bf16 wtf [9][4][64][16]   73728 B (fragment order)
static constexpr size_t WO_B  = 26288128;  // bf16 wof [9][4][64][8]    36864 B (fragment order)
static constexpr size_t SUM_B = 26324992;  // f32 sums [4][128]          2048 B

__device__ __forceinline__ ushort f2bf(float f) {
  uint u = __float_as_uint(f);
  return (ushort)((u + 0x7fffu + ((u >> 16) & 1u)) >> 16);
}

union PackBF { __hip_bfloat162 h[4]; short8 s; };

#define UNPACK_FMA(q, wgt, m)                                  \
  m[0] += (wgt) * __uint_as_float((q).x << 16);                \
  m[1] += (wgt) * __uint_as_float((q).x & 0xffff0000u);        \
  m[2] += (wgt) * __uint_as_float((q).y << 16);                \
  m[3] += (wgt) * __uint_as_float((q).y & 0xffff0000u);        \
  m[4] += (wgt) * __uint_as_float((q).z << 16);                \
  m[5] += (wgt) * __uint_as_float((q).z & 0xffff0000u);        \
  m[6] += (wgt) * __uint_as_float((q).w << 16);                \
  m[7] += (wgt) * __uint_as_float((q).w & 0xffff0000u);

// ---------------- prep: x NCHW->NHWC bf16; w/w_off -> per-lane fragment order; zero sums
__global__ __launch_bounds__(256) void prep_kernel(const float* __restrict__ x,
                                                   const float* __restrict__ w,
                                                   const float* __restrict__ w_off,
                                                   ushort* __restrict__ xt,
                                                   ushort* __restrict__ wt,
                                                   ushort* __restrict__ wo,
                                                   float* __restrict__ sums) {
  int b = blockIdx.x, t = threadIdx.x;
  if (b < 1024) {
    __shared__ float lds[64 * 129];
    int n = b >> 7, h = b & 127;
    const float* xp = x + ((size_t)n * C) * H * W + (size_t)h * W;
    for (int i = t; i < 8192; i += 256) {
      int c = i >> 7, ww = i & 127;
      lds[c * 129 + ww] = xp[(size_t)c * H * W + ww];
    }
    __syncthreads();
    ushort* xo = xt + (((size_t)n * H + h) * W) * C;
    for (int i = t; i < 8192; i += 256) {
      int ww = i >> 6, c = i & 63;
      xo[(size_t)ww * C + c] = f2bf(lds[c * 129 + ww]);
    }
  } else if (b < 1040) {
    // wtf[k][ct][ln][16]: B-frag rows co=ct*16+(ln&15), c = (ln>>4)*8 + (j<8 ? j : 24+j)
    int base = (b - 1024) * 2304;
    for (int i = t; i < 2304; i += 256) {
      int idx = base + i;                    // [0, 36864)
      int k = idx >> 12;
      int r = idx & 4095;
      int ct = r >> 10, ln = (r >> 4) & 63, j = r & 15;
      int co = ct * 16 + (ln & 15);
      int c = ((ln >> 4) << 3) + (j < 8 ? j : 24 + j);
      wt[idx] = f2bf(w[co * 576 + c * 9 + k]);
    }
  } else if (b < 1048) {
    // wof[k][f][ln][8]: o = (f>>1)*16 + (ln&15); c = (ln>>4)*8 + (f&1)*32 + j
    int base = (b - 1040) * 2304;
    for (int i = t; i < 2304; i += 256) {
      int idx = base + i;                    // [0, 18432)
      if (idx < 18432) {
        int k = idx >> 11;
        int r = idx & 2047;
        int f = r >> 9, ln = (r >> 3) & 63, j = r & 7;
        int o = ((f >> 1) << 4) + (ln & 15);
        int c = ((ln >> 4) << 3) + ((f & 1) << 5) + j;
        wo[idx] = (o < 18) ? f2bf(w_off[(o * 64 + c) * 9 + k]) : (ushort)0;
      }
    }
  } else {
    sums[t] = 0.0f;
    sums[t + 256] = 0.0f;
  }
}

// ---------------- offset conv via bf16 MFMA, x-window in LDS; writes sample coords
__global__ __launch_bounds__(256, 4) void offs_kernel(const ushort* __restrict__ xt,
                                                      const ushort* __restrict__ wo,
                                                      const float* __restrict__ b_off,
                                                      float2* __restrict__ cd) {
  int b = blockIdx.x;
  int n = b & 7;                 // XCD swizzle: one image per XCD
  int tile = b >> 3;
  int ty0 = (tile >> 4) << 3;
  int tx0 = (tile & 15) << 3;
  int t = threadIdx.x;
  int wv = t >> 6, ln = t & 63;
  int lr = ln & 15, lg = ln >> 4;
  int mypos = wv * 16 + lr;
  int ph = ty0 + (mypos >> 3), pw = tx0 + (mypos & 7);
  const ushort* xtn = xt + ((size_t)n << 20);

  __shared__ ushort xwin[256 * 64];  // 16x16 texels x 128B, slot-swizzled

  // stage window rows [ty0-4, ty0+11] x cols [tx0-4, tx0+11] (clamped)
  {
    int by = ty0 - 4, bx = tx0 - 4;
#pragma unroll
    for (int i = 0; i < 8; ++i) {
      int chunk = i * 256 + t;
      int texel = chunk >> 3, slot = chunk & 7;
      int ry = texel >> 4, rx = texel & 15;
      int gy = min(max(by + ry, 0), H - 1);
      int gx = min(max(bx + rx, 0), W - 1);
      *(uint4*)&xwin[(texel << 6) + ((slot ^ (rx & 7)) << 3)] =
          *(const uint4*)(xtn + ((uint)((gy << 7) + gx) << 6) + (slot << 3));
    }
  }
  __syncthreads();

  f32x4 acc0 = {0.f, 0.f, 0.f, 0.f}, acc1 = {0.f, 0.f, 0.f, 0.f};
#pragma unroll
  for (int k = 0; k < 9; ++k) {
    int ky = k / 3 - 1, kx = k % 3 - 1;
    int gy = ph + ky, gx = pw + kx;
    bool v = (gy >= 0) & (gy < H) & (gx >= 0) & (gx < W);
    uint msk = v ? 0xffffffffu : 0u;
    int wry = (mypos >> 3) + 4 + ky, wrx = (mypos & 7) + 4 + kx;
    int texel = (wry << 4) + wrx;
    uint4 a = *(const uint4*)&xwin[(texel << 6) + ((lg ^ (wrx & 7)) << 3)];
    uint4 bq = *(const uint4*)&xwin[(texel << 6) + (((lg + 4) ^ (wrx & 7)) << 3)];
    a.x &= msk; a.y &= msk; a.z &= msk; a.w &= msk;
    bq.x &= msk; bq.y &= msk; bq.z &= msk; bq.w &= msk;
    short8 sa = *(short8*)&a, sb = *(short8*)&bq;
    const ushort* wk = wo + (((k << 2)) << 9) + (ln << 3);  // wof[k][f][ln][8]
    short8 b00 = *(const short8*)(wk);
    short8 b01 = *(const short8*)(wk + 512);
    short8 b10 = *(const short8*)(wk + 1024);
    short8 b11 = *(const short8*)(wk + 1536);
    acc0 = __builtin_amdgcn_mfma_f32_16x16x32_bf16(sa, b00, acc0, 0, 0, 0);
    acc0 = __builtin_amdgcn_mfma_f32_16x16x32_bf16(sb, b01, acc0, 0, 0, 0);
    acc1 = __builtin_amdgcn_mfma_f32_16x16x32_bf16(sa, b10, acc1, 0, 0, 0);
    acc1 = __builtin_amdgcn_mfma_f32_16x16x32_bf16(sb, b11, acc1, 0, 0, 0);
  }
  // D[pos][o]: lane holds o = ot*16+lr (cols), pos = wv*16 + lg*4 + r (rows)
  float bo0 = b_off[lr];
  float bo1 = (lr < 2) ? b_off[16 + lr] : 0.f;
  int rh[4], rw[4];
#pragma unroll
  for (int r = 0; r < 4; ++r) {
    int pos = wv * 16 + lg * 4 + r;
    rh[r] = ty0 + (pos >> 3);
    rw[r] = tx0 + (pos & 7);
  }
  float v0[4], p0[4], v1[4], p1[4];
#pragma unroll
  for (int r = 0; r < 4; ++r) { v0[r] = acc0[r] + bo0; v1[r] = acc1[r] + bo1; }
#pragma unroll
  for (int r = 0; r < 4; ++r) { p0[r] = __shfl_xor(v0[r], 1); p1[r] = __shfl_xor(v1[r], 1); }
  if (!(lr & 1)) {
    int k = lr >> 1;  // 0..7
    int ky = k / 3 - 1, kx = k % 3 - 1;
    float2* cdn = cd + (((size_t)n * 9 + k) << 14);
#pragma unroll
    for (int r = 0; r < 4; ++r)
      cdn[(rh[r] << 7) + rw[r]] = make_float2((float)(rh[r] + ky) + v0[r],
                                              (float)(rw[r] + kx) + p0[r]);
    if (lr == 0) {
      float2* cd8 = cd + (((size_t)n * 9 + 8) << 14);
#pragma unroll
      for (int r = 0; r < 4; ++r)
        cd8[(rh[r] << 7) + rw[r]] = make_float2((float)(rh[r] + 1) + v1[r],
                                                (float)(rw[r] + 1) + p1[r]);
    }
  }
}

// ---------------- deformable conv: LDS-window bilinear gather -> bf16 MFMA
__global__ __launch_bounds__(256, 4) void conv_kernel(const ushort* __restrict__ xt,
                                                      const float2* __restrict__ cd,
                                                      const ushort* __restrict__ wt,
                                                      const float* __restrict__ bias,
                                                      float* __restrict__ out,
                                                      float* __restrict__ sums) {
  int b = blockIdx.x;
  int n = b & 7;                 // XCD swizzle: one image per XCD
  int tile = b >> 3;
  int ty0 = (tile >> 4) << 3;
  int tx0 = (tile & 15) << 3;
  int t = threadIdx.x;
  int wv = t >> 6, ln = t & 63;
  int lr = ln & 15, lg = ln >> 4;
  int mypos = wv * 16 + lr;
  int ph = ty0 + (mypos >> 3), pw = tx0 + (mypos & 7);
  int cb = lg << 3;
  int by = ty0 - 4, bx = tx0 - 4;

  __shared__ ushort xwin[256 * 64];  // 32 KB window
  __shared__ float red[4][64][2];

  const ushort* xtn = xt + ((size_t)n << 20);
  const float2* cdn = cd + (((size_t)n * 9) << 14) + (ph << 7) + pw;

  // prefetch all 9 sample coords (one latency)
  float2 cd2[9];
#pragma unroll
  for (int k = 0; k < 9; ++k) cd2[k] = cdn[(size_t)k << 14];

  // stage window
#pragma unroll
  for (int i = 0; i < 8; ++i) {
    int chunk = i * 256 + t;
    int texel = chunk >> 3, slot = chunk & 7;
    int ry = texel >> 4, rx = texel & 15;
    int gy = min(max(by + ry, 0), H - 1);
    int gx = min(max(bx + rx, 0), W - 1);
    *(uint4*)&xwin[(texel << 6) + ((slot ^ (rx & 7)) << 3)] =
        *(const uint4*)(xtn + ((uint)((gy << 7) + gx) << 6) + (slot << 3));
  }
  __syncthreads();

  f32x4 acc[4];
#pragma unroll
  for (int ct = 0; ct < 4; ++ct) acc[ct] = (f32x4)(0.f);

#pragma unroll
  for (int k = 0; k < 9; ++k) {
    float ys = cd2[k].x, xs = cd2[k].y;
    float y0f = floorf(ys), x0f = floorf(xs);
    float wy = ys - y0f, wx = xs - x0f;
    int iy0 = (int)y0f, ix0 = (int)x0f;
    int iy1 = iy0 + 1, ix1 = ix0 + 1;
    bool y0v = (iy0 >= 0) & (iy0 < H);
    bool y1v = (iy1 >= 0) & (iy1 < H);
    bool x0v = (ix0 >= 0) & (ix0 < W);
    bool x1v = (ix1 >= 0) & (ix1 < W);
    int yc0 = min(max(iy0, 0), H - 1), yc1 = min(max(iy1, 0), H - 1);
    int xc0 = min(max(ix0, 0), W - 1), xc1 = min(max(ix1, 0), W - 1);
    float w00 = (1.f - wy) * (1.f - wx) * (float)(y0v & x0v);
    float w01 = (1.f - wy) * wx * (float)(y0v & x1v);
    float w10 = wy * (1.f - wx) * (float)(y1v & x0v);
    float w11 = wy * wx * (float)(y1v & x1v);

    float m0[8] = {0.f, 0.f, 0.f, 0.f, 0.f, 0.f, 0.f, 0.f};
    float m1[8] = {0.f, 0.f, 0.f, 0.f, 0.f, 0.f, 0.f, 0.f};

#define CORNER(yc, xc, wgt) {                                                   \
    int ry_ = (yc) - by, rx_ = (xc) - bx;                                       \
    int ryc_ = min(max(ry_, 0), 15), rxc_ = min(max(rx_, 0), 15);               \
    int tex_ = (ryc_ << 4) + rxc_;                                              \
    uint4 qa_ = *(const uint4*)&xwin[(tex_ << 6) + ((lg ^ (rxc_ & 7)) << 3)];   \
    uint4 qb_ = *(const uint4*)&xwin[(tex_ << 6) + (((lg + 4) ^ (rxc_ & 7)) << 3)]; \
    if (__builtin_expect((((uint)ry_ >= 16u) | ((uint)rx_ >= 16u)) && (wgt) != 0.f, 0)) { \
      uint p_ = (uint)(((yc) << 7) + (xc)) << 6;                                \
      qa_ = *(const uint4*)(xtn + p_ + cb);                                     \
      qb_ = *(const uint4*)(xtn + p_ + cb + 32);                                \
    }                                                                           \
    UNPACK_FMA(qa_, wgt, m0); UNPACK_FMA(qb_, wgt, m1);                         \
  }

    CORNER(yc0, xc0, w00);
    CORNER(yc0, xc1, w01);
    CORNER(yc1, xc0, w10);
    CORNER(yc1, xc1, w11);
#undef CORNER

    PackBF a0, a1;
#pragma unroll
    for (int j = 0; j < 4; ++j) {
      a0.h[j] = __float22bfloat162_rn(make_float2(m0[2 * j], m0[2 * j + 1]));
      a1.h[j] = __float22bfloat162_rn(make_float2(m1[2 * j], m1[2 * j + 1]));
    }
    // dense fragment-order B loads: wtf[k][ct][ln][16]
    const ushort* wk = wt + (k << 12) + (ln << 4);
#pragma unroll
    for (int ct = 0; ct < 4; ++ct) {
      short8 b0 = *(const short8*)(wk + (ct << 10));
      short8 b1 = *(const short8*)(wk + (ct << 10) + 8);
      acc[ct] = __builtin_amdgcn_mfma_f32_16x16x32_bf16(a0.s, b0, acc[ct], 0, 0, 0);
      acc[ct] = __builtin_amdgcn_mfma_f32_16x16x32_bf16(a1.s, b1, acc[ct], 0, 0, 0);
    }
  }

  // epilogue: D[pos][co]; lane: co = ct*16+lr, pos = wv*16 + lg*4 + r
  float bi[4];
#pragma unroll
  for (int ct = 0; ct < 4; ++ct) bi[ct] = bias[ct * 16 + lr];
  int phw[4];
#pragma unroll
  for (int r = 0; r < 4; ++r) {
    int pos = wv * 16 + lg * 4 + r;
    phw[r] = ((ty0 + (pos >> 3)) << 7) + tx0 + (pos & 7);
  }
  float s1[4], s2[4];
#pragma unroll
  for (int ct = 0; ct < 4; ++ct) { s1[ct] = 0.f; s2[ct] = 0.f; }
#pragma unroll
  for (int ct = 0; ct < 4; ++ct) {
    size_t cbase = ((size_t)(n * 64 + ct * 16 + lr)) << 14;
#pragma unroll
    for (int r = 0; r < 4; ++r) {
      float v = acc[ct][r] + bi[ct];
      out[cbase + phw[r]] = v;
      s1[ct] += v;
      s2[ct] += v * v;
    }
  }
#pragma unroll
  for (int ct = 0; ct < 4; ++ct) {
    s1[ct] += __shfl_xor(s1[ct], 16);
    s1[ct] += __shfl_xor(s1[ct], 32);
    s2[ct] += __shfl_xor(s2[ct], 16);
    s2[ct] += __shfl_xor(s2[ct], 32);
  }
  if (lg == 0) {
#pragma unroll
    for (int ct = 0; ct < 4; ++ct) {
      red[wv][ct * 16 + lr][0] = s1[ct];
      red[wv][ct * 16 + lr][1] = s2[ct];
    }
  }
  __syncthreads();
  if (t < 128) {
    int co = t & 63, j = t >> 6;
    float s = red[0][co][j] + red[1][co][j] + red[2][co][j] + red[3][co][j];
    atomicAdd(&sums[(b & 3) * 128 + j * 64 + co], s);
  }
}

// ---------------- BN apply (in place on d_out)
__global__ __launch_bounds__(256) void bn_kernel(float* __restrict__ out,
                                                 const float* __restrict__ sums,
                                                 const float* __restrict__ gamma,
                                                 const float* __restrict__ beta) {
  size_t i4 = (size_t)blockIdx.x * 256 + threadIdx.x;
  size_t e = i4 * 4;
  int co = (int)((e >> 14) & 63);
  float s1 = sums[co] + sums[128 + co] + sums[256 + co] + sums[384 + co];
  float s2 = sums[64 + co] + sums[192 + co] + sums[320 + co] + sums[448 + co];
  const float inv_n = 1.f / 131072.f;
  float mean = s1 * inv_n;
  float var = s2 * inv_n - mean * mean;
  float iv = rsqrtf(var + 1e-5f);
  float sc = gamma[co] * iv;
  float sh = beta[co] - mean * sc;
  float4 v = ((float4*)out)[i4];
  v.x = v.x * sc + sh;
  v.y = v.y * sc + sh;
  v.z = v.z * sc + sh;
  v.w = v.w * sc + sh;
  ((float4*)out)[i4] = v;
}

extern "C" void kernel_launch(void* const* d_in, const int* in_sizes, int n_in,
                              void* d_out, int out_size, void* d_ws, size_t ws_size,
                              hipStream_t stream) {
  (void)in_sizes; (void)n_in; (void)out_size; (void)ws_size;
  const float* x     = (const float*)d_in[0];
  const float* w_off = (const float*)d_in[1];
  const float* b_off = (const float*)d_in[2];
  const float* w     = (const float*)d_in[3];
  const float* bias  = (const float*)d_in[4];
  const float* gamma = (const float*)d_in[5];
  const float* beta  = (const float*)d_in[6];
  uint8_t* wsb = (uint8_t*)d_ws;
  ushort* xtp  = (ushort*)(wsb + XT_B);
  float2* cdp  = (float2*)(wsb + CD_B);
  ushort* wtp  = (ushort*)(wsb + WT_B);
  ushort* wop  = (ushort*)(wsb + WO_B);
  float* sums  = (float*)(wsb + SUM_B);
  float* out   = (float*)d_out;

  hipLaunchKernelGGL(prep_kernel, dim3(1049), dim3(256), 0, stream, x, w, w_off, xtp, wtp, wop, sums);
  hipLaunchKernelGGL(offs_kernel, dim3(2048), dim3(256), 0, stream, xtp, wop, b_off, cdp);
  hipLaunchKernelGGL(conv_kernel, dim3(2048), dim3(256), 0, stream, xtp, cdp, wtp, bias, out, sums);
  hipLaunchKernelGGL(bn_kernel, dim3(8192), dim3(256), 0, stream, out, sums, gamma, beta);
}

// Round 7
// 163.934 us; speedup vs baseline: 1.7618x; 1.0280x over previous
//
#include <hip/hip_runtime.h>
#include <hip/hip_fp16.h>

#define H 128
#define W 128
#define C 64
#define NB 8

typedef __attribute__((ext_vector_type(4))) float f32x4;
typedef __attribute__((ext_vector_type(8))) _Float16 f16x8;

// ws layout (bytes)
static constexpr size_t XT_B  = 0;         // f16 xt [N][H][W][C]    16777216 B
static constexpr size_t CD_B  = 16777216;  // float2 cd [N][9][H][W]  9437184 B
static constexpr size_t WT_B  = 26214400;  // f16 wtf [9][4][64][16]    73728 B (fragment order)
static constexpr size_t WO_B  = 26288128;  // f16 wof [9][4][64][8]     36864 B (fragment order)
static constexpr size_t SUM_B = 26324992;  // f32 sums [4][128]          2048 B
static constexpr size_t PB_B  = 26327040;  // f16 preBN [N][64][H][W] 16777216 B (total 43.10 MB)

__device__ __forceinline__ ushort f2h(float f) {
  __half h = __float2half_rn(f);
  return *reinterpret_cast<ushort*>(&h);
}

union QH  { uint4 q; f16x8 h; };
union AH  { __half2 h[4]; f16x8 v; };
union PK2 { __half2 h[2]; uint2 u; };

// ---------------- prep: x NCHW->NHWC f16; w/w_off -> per-lane fragment order f16; zero sums
__global__ __launch_bounds__(256) void prep_kernel(const float* __restrict__ x,
                                                   const float* __restrict__ w,
                                                   const float* __restrict__ w_off,
                                                   ushort* __restrict__ xt,
                                                   ushort* __restrict__ wt,
                                                   ushort* __restrict__ wo,
                                                   float* __restrict__ sums) {
  int b = blockIdx.x, t = threadIdx.x;
  if (b < 1024) {
    __shared__ float lds[64 * 129];
    int n = b >> 7, h = b & 127;
    const float* xp = x + ((size_t)n * C) * H * W + (size_t)h * W;
    for (int i = t; i < 8192; i += 256) {
      int c = i >> 7, ww = i & 127;
      lds[c * 129 + ww] = xp[(size_t)c * H * W + ww];
    }
    __syncthreads();
    ushort* xo = xt + (((size_t)n * H + h) * W) * C;
    for (int i = t; i < 8192; i += 256) {
      int ww = i >> 6, c = i & 63;
      xo[(size_t)ww * C + c] = f2h(lds[c * 129 + ww]);
    }
  } else if (b < 1040) {
    // wtf[k][ct][ln][16]: co = ct*16+(ln&15), c = (ln>>4)*8 + (j<8 ? j : 24+j)
    int base = (b - 1024) * 2304;
    for (int i = t; i < 2304; i += 256) {
      int idx = base + i;                    // [0, 36864)
      int k = idx >> 12;
      int r = idx & 4095;
      int ct = r >> 10, ln = (r >> 4) & 63, j = r & 15;
      int co = ct * 16 + (ln & 15);
      int c = ((ln >> 4) << 3) + (j < 8 ? j : 24 + j);
      wt[idx] = f2h(w[co * 576 + c * 9 + k]);
    }
  } else if (b < 1048) {
    // wof[k][f][ln][8]: o = (f>>1)*16 + (ln&15); c = (ln>>4)*8 + (f&1)*32 + j
    int base = (b - 1040) * 2304;
    for (int i = t; i < 2304; i += 256) {
      int idx = base + i;                    // [0, 18432)
      if (idx < 18432) {
        int k = idx >> 11;
        int r = idx & 2047;
        int f = r >> 9, ln = (r >> 3) & 63, j = r & 7;
        int o = ((f >> 1) << 4) + (ln & 15);
        int c = ((ln >> 4) << 3) + ((f & 1) << 5) + j;
        wo[idx] = (o < 18) ? f2h(w_off[(o * 64 + c) * 9 + k]) : (ushort)0;
      }
    }
  } else {
    sums[t] = 0.0f;
    sums[t + 256] = 0.0f;
  }
}

// ---------------- offset conv via f16 MFMA, x-window in LDS; writes sample coords
__global__ __launch_bounds__(256, 4) void offs_kernel(const ushort* __restrict__ xt,
                                                      const ushort* __restrict__ wo,
                                                      const float* __restrict__ b_off,
                                                      float2* __restrict__ cd) {
  int b = blockIdx.x;
  int n = b & 7;                 // XCD swizzle: one image per XCD
  int tile = b >> 3;
  int ty0 = (tile >> 4) << 3;
  int tx0 = (tile & 15) << 3;
  int t = threadIdx.x;
  int wv = t >> 6, ln = t & 63;
  int lr = ln & 15, lg = ln >> 4;
  int mypos = wv * 16 + lr;
  int ph = ty0 + (mypos >> 3), pw = tx0 + (mypos & 7);
  const ushort* xtn = xt + ((size_t)n << 20);

  __shared__ ushort xwin[256 * 64];  // 16x16 texels x 128B, slot-swizzled

  {
    int by = ty0 - 4, bx = tx0 - 4;
#pragma unroll
    for (int i = 0; i < 8; ++i) {
      int chunk = i * 256 + t;
      int texel = chunk >> 3, slot = chunk & 7;
      int ry = texel >> 4, rx = texel & 15;
      int gy = min(max(by + ry, 0), H - 1);
      int gx = min(max(bx + rx, 0), W - 1);
      *(uint4*)&xwin[(texel << 6) + ((slot ^ (rx & 7)) << 3)] =
          *(const uint4*)(xtn + ((uint)((gy << 7) + gx) << 6) + (slot << 3));
    }
  }
  __syncthreads();

  f32x4 acc0 = {0.f, 0.f, 0.f, 0.f}, acc1 = {0.f, 0.f, 0.f, 0.f};
#pragma unroll
  for (int k = 0; k < 9; ++k) {
    int ky = k / 3 - 1, kx = k % 3 - 1;
    int gy = ph + ky, gx = pw + kx;
    bool v = (gy >= 0) & (gy < H) & (gx >= 0) & (gx < W);
    uint msk = v ? 0xffffffffu : 0u;
    int wry = (mypos >> 3) + 4 + ky, wrx = (mypos & 7) + 4 + kx;
    int texel = (wry << 4) + wrx;
    QH qa, qb;
    qa.q = *(const uint4*)&xwin[(texel << 6) + ((lg ^ (wrx & 7)) << 3)];
    qb.q = *(const uint4*)&xwin[(texel << 6) + (((lg + 4) ^ (wrx & 7)) << 3)];
    qa.q.x &= msk; qa.q.y &= msk; qa.q.z &= msk; qa.q.w &= msk;
    qb.q.x &= msk; qb.q.y &= msk; qb.q.z &= msk; qb.q.w &= msk;
    const ushort* wk = wo + (k << 11) + (ln << 3);  // wof[k][f][ln][8]
    f16x8 b00 = *(const f16x8*)(const void*)(wk);
    f16x8 b01 = *(const f16x8*)(const void*)(wk + 512);
    f16x8 b10 = *(const f16x8*)(const void*)(wk + 1024);
    f16x8 b11 = *(const f16x8*)(const void*)(wk + 1536);
    acc0 = __builtin_amdgcn_mfma_f32_16x16x32_f16(qa.h, b00, acc0, 0, 0, 0);
    acc0 = __builtin_amdgcn_mfma_f32_16x16x32_f16(qb.h, b01, acc0, 0, 0, 0);
    acc1 = __builtin_amdgcn_mfma_f32_16x16x32_f16(qa.h, b10, acc1, 0, 0, 0);
    acc1 = __builtin_amdgcn_mfma_f32_16x16x32_f16(qb.h, b11, acc1, 0, 0, 0);
  }
  // D[pos][o]: lane holds o = ot*16+lr (cols), pos = wv*16 + lg*4 + r (rows)
  float bo0 = b_off[lr];
  float bo1 = (lr < 2) ? b_off[16 + lr] : 0.f;
  int rh[4], rw[4];
#pragma unroll
  for (int r = 0; r < 4; ++r) {
    int pos = wv * 16 + lg * 4 + r;
    rh[r] = ty0 + (pos >> 3);
    rw[r] = tx0 + (pos & 7);
  }
  float v0[4], p0[4], v1[4], p1[4];
#pragma unroll
  for (int r = 0; r < 4; ++r) { v0[r] = acc0[r] + bo0; v1[r] = acc1[r] + bo1; }
#pragma unroll
  for (int r = 0; r < 4; ++r) { p0[r] = __shfl_xor(v0[r], 1); p1[r] = __shfl_xor(v1[r], 1); }
  if (!(lr & 1)) {
    int k = lr >> 1;  // 0..7
    int ky = k / 3 - 1, kx = k % 3 - 1;
    float2* cdn = cd + (((size_t)n * 9 + k) << 14);
#pragma unroll
    for (int r = 0; r < 4; ++r)
      cdn[(rh[r] << 7) + rw[r]] = make_float2((float)(rh[r] + ky) + v0[r],
                                              (float)(rw[r] + kx) + p0[r]);
    if (lr == 0) {
      float2* cd8 = cd + (((size_t)n * 9 + 8) << 14);
#pragma unroll
      for (int r = 0; r < 4; ++r)
        cd8[(rh[r] << 7) + rw[r]] = make_float2((float)(rh[r] + 1) + v1[r],
                                                (float)(rw[r] + 1) + p1[r]);
    }
  }
}

// ---------------- deformable conv: LDS-window gather, packed-f16 bilinear -> f16 MFMA
__global__ __launch_bounds__(256, 4) void conv_kernel(const ushort* __restrict__ xt,
                                                      const float2* __restrict__ cd,
                                                      const ushort* __restrict__ wt,
                                                      const float* __restrict__ bias,
                                                      ushort* __restrict__ pb,
                                                      float* __restrict__ sums) {
  int b = blockIdx.x;
  int n = b & 7;                 // XCD swizzle: one image per XCD
  int tile = b >> 3;
  int ty0 = (tile >> 4) << 3;
  int tx0 = (tile & 15) << 3;
  int t = threadIdx.x;
  int wv = t >> 6, ln = t & 63;
  int lr = ln & 15, lg = ln >> 4;
  int mypos = wv * 16 + lr;
  int ph = ty0 + (mypos >> 3), pw = tx0 + (mypos & 7);
  int cb = lg << 3;
  int by = ty0 - 4, bx = tx0 - 4;

  __shared__ ushort xwin[256 * 64];  // 32 KB window
  __shared__ float red[4][64][2];

  const ushort* xtn = xt + ((size_t)n << 20);
  const float2* cdn = cd + (((size_t)n * 9) << 14) + (ph << 7) + pw;

  float2 cd2[9];
#pragma unroll
  for (int k = 0; k < 9; ++k) cd2[k] = cdn[(size_t)k << 14];

#pragma unroll
  for (int i = 0; i < 8; ++i) {
    int chunk = i * 256 + t;
    int texel = chunk >> 3, slot = chunk & 7;
    int ry = texel >> 4, rx = texel & 15;
    int gy = min(max(by + ry, 0), H - 1);
    int gx = min(max(bx + rx, 0), W - 1);
    *(uint4*)&xwin[(texel << 6) + ((slot ^ (rx & 7)) << 3)] =
        *(const uint4*)(xtn + ((uint)((gy << 7) + gx) << 6) + (slot << 3));
  }
  __syncthreads();

  f32x4 acc[4];
#pragma unroll
  for (int ct = 0; ct < 4; ++ct) acc[ct] = (f32x4)(0.f);
  const __half2 HZ = __floats2half2_rn(0.f, 0.f);

#pragma unroll
  for (int k = 0; k < 9; ++k) {
    float ys = cd2[k].x, xs = cd2[k].y;
    float y0f = floorf(ys), x0f = floorf(xs);
    float wy = ys - y0f, wx = xs - x0f;
    int iy0 = (int)y0f, ix0 = (int)x0f;
    int iy1 = iy0 + 1, ix1 = ix0 + 1;
    bool y0v = (iy0 >= 0) & (iy0 < H);
    bool y1v = (iy1 >= 0) & (iy1 < H);
    bool x0v = (ix0 >= 0) & (ix0 < W);
    bool x1v = (ix1 >= 0) & (ix1 < W);
    int yc0 = min(max(iy0, 0), H - 1), yc1 = min(max(iy1, 0), H - 1);
    int xc0 = min(max(ix0, 0), W - 1), xc1 = min(max(ix1, 0), W - 1);
    float w00 = (1.f - wy) * (1.f - wx) * (float)(y0v & x0v);
    float w01 = (1.f - wy) * wx * (float)(y0v & x1v);
    float w10 = wy * (1.f - wx) * (float)(y1v & x0v);
    float w11 = wy * wx * (float)(y1v & x1v);
    __half2 W00 = __float2half2_rn(w00), W01 = __float2half2_rn(w01);
    __half2 W10 = __float2half2_rn(w10), W11 = __float2half2_rn(w11);

    AH m0, m1;
#pragma unroll
    for (int j = 0; j < 4; ++j) { m0.h[j] = HZ; m1.h[j] = HZ; }

#define CORNER(yc, xc, wgt, WW) {                                               \
    int ry_ = (yc) - by, rx_ = (xc) - bx;                                       \
    int ryc_ = min(max(ry_, 0), 15), rxc_ = min(max(rx_, 0), 15);               \
    int tex_ = (ryc_ << 4) + rxc_;                                              \
    uint4 qa_ = *(const uint4*)&xwin[(tex_ << 6) + ((lg ^ (rxc_ & 7)) << 3)];   \
    uint4 qb_ = *(const uint4*)&xwin[(tex_ << 6) + (((lg + 4) ^ (rxc_ & 7)) << 3)]; \
    if (__builtin_expect((((uint)ry_ >= 16u) | ((uint)rx_ >= 16u)) && (wgt) != 0.f, 0)) { \
      uint p_ = (uint)(((yc) << 7) + (xc)) << 6;                                \
      qa_ = *(const uint4*)(xtn + p_ + cb);                                     \
      qb_ = *(const uint4*)(xtn + p_ + cb + 32);                                \
    }                                                                           \
    const __half2* pa_ = (const __half2*)&qa_;                                  \
    const __half2* pb_ = (const __half2*)&qb_;                                  \
    m0.h[0] = __hfma2(WW, pa_[0], m0.h[0]);                                     \
    m0.h[1] = __hfma2(WW, pa_[1], m0.h[1]);                                     \
    m0.h[2] = __hfma2(WW, pa_[2], m0.h[2]);                                     \
    m0.h[3] = __hfma2(WW, pa_[3], m0.h[3]);                                     \
    m1.h[0] = __hfma2(WW, pb_[0], m1.h[0]);                                     \
    m1.h[1] = __hfma2(WW, pb_[1], m1.h[1]);                                     \
    m1.h[2] = __hfma2(WW, pb_[2], m1.h[2]);                                     \
    m1.h[3] = __hfma2(WW, pb_[3], m1.h[3]);                                     \
  }

    CORNER(yc0, xc0, w00, W00);
    CORNER(yc0, xc1, w01, W01);
    CORNER(yc1, xc0, w10, W10);
    CORNER(yc1, xc1, w11, W11);
#undef CORNER

    const ushort* wk = wt + (k << 12) + (ln << 4);
#pragma unroll
    for (int ct = 0; ct < 4; ++ct) {
      f16x8 b0 = *(const f16x8*)(const void*)(wk + (ct << 10));
      f16x8 b1 = *(const f16x8*)(const void*)(wk + (ct << 10) + 8);
      acc[ct] = __builtin_amdgcn_mfma_f32_16x16x32_f16(m0.v, b0, acc[ct], 0, 0, 0);
      acc[ct] = __builtin_amdgcn_mfma_f32_16x16x32_f16(m1.v, b1, acc[ct], 0, 0, 0);
    }
  }

  // epilogue: D[pos][co]; lane: co = ct*16+lr, pos = wv*16 + lg*4 + r (4 consecutive w)
  float bi[4];
#pragma unroll
  for (int ct = 0; ct < 4; ++ct) bi[ct] = bias[ct * 16 + lr];
  int pos0 = wv * 16 + lg * 4;
  int phw0 = ((ty0 + (pos0 >> 3)) << 7) + tx0 + (pos0 & 7);
  float s1[4], s2[4];
#pragma unroll
  for (int ct = 0; ct < 4; ++ct) {
    float v0 = acc[ct][0] + bi[ct];
    float v1 = acc[ct][1] + bi[ct];
    float v2 = acc[ct][2] + bi[ct];
    float v3 = acc[ct][3] + bi[ct];
    size_t cbase = ((size_t)(n * 64 + ct * 16 + lr) << 14) + phw0;
    PK2 pk;
    pk.h[0] = __floats2half2_rn(v0, v1);
    pk.h[1] = __floats2half2_rn(v2, v3);
    *(uint2*)&pb[cbase] = pk.u;
    s1[ct] = v0 + v1 + v2 + v3;
    s2[ct] = v0 * v0 + v1 * v1 + v2 * v2 + v3 * v3;
  }
#pragma unroll
  for (int ct = 0; ct < 4; ++ct) {
    s1[ct] += __shfl_xor(s1[ct], 16);
    s1[ct] += __shfl_xor(s1[ct], 32);
    s2[ct] += __shfl_xor(s2[ct], 16);
    s2[ct] += __shfl_xor(s2[ct], 32);
  }
  if (lg == 0) {
#pragma unroll
    for (int ct = 0; ct < 4; ++ct) {
      red[wv][ct * 16 + lr][0] = s1[ct];
      red[wv][ct * 16 + lr][1] = s2[ct];
    }
  }
  __syncthreads();
  if (t < 128) {
    int co = t & 63, j = t >> 6;
    float s = red[0][co][j] + red[1][co][j] + red[2][co][j] + red[3][co][j];
    atomicAdd(&sums[(b & 3) * 128 + j * 64 + co], s);
  }
}

// ---------------- BN apply: read preBN f16, write f32 out
__global__ __launch_bounds__(256) void bn_kernel(const ushort* __restrict__ pb,
                                                 float* __restrict__ out,
                                                 const float* __restrict__ sums,
                                                 const float* __restrict__ gamma,
                                                 const float* __restrict__ beta) {
  size_t i4 = (size_t)blockIdx.x * 256 + threadIdx.x;
  size_t e = i4 * 4;
  int co = (int)((e >> 14) & 63);
  float s1 = sums[co] + sums[128 + co] + sums[256 + co] + sums[384 + co];
  float s2 = sums[64 + co] + sums[192 + co] + sums[320 + co] + sums[448 + co];
  const float inv_n = 1.f / 131072.f;
  float mean = s1 * inv_n;
  float var = s2 * inv_n - mean * mean;
  float iv = rsqrtf(var + 1e-5f);
  float sc = gamma[co] * iv;
  float sh = beta[co] - mean * sc;
  PK2 q;
  q.u = ((const uint2*)pb)[i4];
  float2 f0 = __half22float2(q.h[0]);
  float2 f1 = __half22float2(q.h[1]);
  float4 o;
  o.x = f0.x * sc + sh;
  o.y = f0.y * sc + sh;
  o.z = f1.x * sc + sh;
  o.w = f1.y * sc + sh;
  ((float4*)out)[i4] = o;
}

extern "C" void kernel_launch(void* const* d_in, const int* in_sizes, int n_in,
                              void* d_out, int out_size, void* d_ws, size_t ws_size,
                              hipStream_t stream) {
  (void)in_sizes; (void)n_in; (void)out_size; (void)ws_size;
  const float* x     = (const float*)d_in[0];
  const float* w_off = (const float*)d_in[1];
  const float* b_off = (const float*)d_in[2];
  const float* w     = (const float*)d_in[3];
  const float* bias  = (const float*)d_in[4];
  const float* gamma = (const float*)d_in[5];
  const float* beta  = (const float*)d_in[6];
  uint8_t* wsb = (uint8_t*)d_ws;
  ushort* xtp  = (ushort*)(wsb + XT_B);
  float2* cdp  = (float2*)(wsb + CD_B);
  ushort* wtp  = (ushort*)(wsb + WT_B);
  ushort* wop  = (ushort*)(wsb + WO_B);
  float* sums  = (float*)(wsb + SUM_B);
  ushort* pbp  = (ushort*)(wsb + PB_B);
  float* out   = (float*)d_out;

  hipLaunchKernelGGL(prep_kernel, dim3(1049), dim3(256), 0, stream, x, w, w_off, xtp, wtp, wop, sums);
  hipLaunchKernelGGL(offs_kernel, dim3(2048), dim3(256), 0, stream, xtp, wop, b_off, cdp);
  hipLaunchKernelGGL(conv_kernel, dim3(2048), dim3(256), 0, stream, xtp, cdp, wtp, bias, pbp, sums);
  hipLaunchKernelGGL(bn_kernel, dim3(8192), dim3(256), 0, stream, pbp, out, sums, gamma, beta);
}